// Round 3
// baseline (159.968 us; speedup 1.0000x reference)
//
#include <hip/hip_runtime.h>
#include <hip/hip_bf16.h>

typedef float f32x4 __attribute__((ext_vector_type(4)));
typedef short short8 __attribute__((ext_vector_type(8)));

#define SEQ_LEN 32
#define EMBED_DIM 64
#define FC_DIM 100
#define BATCH 512
#define AS 132      // fp32 row stride for A_s/B_s: 2-way bank alias only (free)
#define ES 80       // bf16 row stride for emb_s: 160B rows -> 16B-aligned vector ops

union FragAB { short8 s; __bf16 h[8]; };   // MFMA operand ABI (short8, guide-verified)

// All global float tensors are fp32 (per reference: JAX default dtypes).
// bf16 is used ONLY internally for MFMA fragments; accumulation is fp32.
//
// One block per batch element. 256 threads = 4 waves.
// A: gather embedding rows, fp32 -> bf16 -> LDS. Zero-pad A_s/B_s cols 100..131.
// B: first FC via MFMA (M=32, N=208, K=64): A_s[c][f] = embs·Wa^T,
//    B_s[a][f] = embs·Wb^T + b1, fp32 in LDS.
// D: pair loop: per group (16 c-rows, 8 a's): h1 = relu(A+B) built in-register
//    in A-operand layout (A[m=lane&15][k=quad*8+j]), cvt bf16, MFMA vs
//    register-resident Wf2 B-fragments, second relu, lane-local column sums.
// E: LDS tree-reduce column sums -> x_s[100].
// F: out[b,t] = b2[iv] + W2[iv,:]·concat(x_s, uemb)   (pure fp32, LDS reduce)
__global__ __launch_bounds__(256, 2) void cosrec_fused(
    const int* __restrict__ seq_var, const int* __restrict__ user_var,
    const int* __restrict__ item_var, const float* __restrict__ item_emb,
    const float* __restrict__ user_emb, const float* __restrict__ W2,
    const float* __restrict__ b2, const float* __restrict__ W1,
    const float* __restrict__ b1, const float* __restrict__ Wf2,
    const float* __restrict__ bf2, float* __restrict__ out)
{
  __shared__ __align__(16) float A_s[SEQ_LEN * AS];
  __shared__ __align__(16) float B_s[SEQ_LEN * AS];
  __shared__ float red_s[16 * 112];
  __shared__ float x_s[112];
  __shared__ __align__(16) __bf16 emb_s[SEQ_LEN * ES];

  const int b = blockIdx.x;
  const int t = threadIdx.x;
  const int w = t >> 6;
  const int l = t & 63;
  const int l15 = l & 15;
  const int q = l >> 4;

  // ---- Wf2 (fp32) -> register B-fragments: lane holds Wf2[g=nt*16+l15][f=ks*32+q*8+j]
  FragAB wfrag[7][4];
  #pragma unroll
  for (int nt = 0; nt < 7; ++nt) {
    const int gg = nt * 16 + l15;
    #pragma unroll
    for (int ks = 0; ks < 4; ++ks) {
      const int f0 = ks * 32 + q * 8;
      if (gg < FC_DIM && ks < 3) {            // f0+7 <= 95 < 100, 32B-aligned
        const float4 u0 = *(const float4*)(Wf2 + gg * FC_DIM + f0);
        const float4 u1 = *(const float4*)(Wf2 + gg * FC_DIM + f0 + 4);
        wfrag[nt][ks].h[0] = (__bf16)u0.x; wfrag[nt][ks].h[1] = (__bf16)u0.y;
        wfrag[nt][ks].h[2] = (__bf16)u0.z; wfrag[nt][ks].h[3] = (__bf16)u0.w;
        wfrag[nt][ks].h[4] = (__bf16)u1.x; wfrag[nt][ks].h[5] = (__bf16)u1.y;
        wfrag[nt][ks].h[6] = (__bf16)u1.z; wfrag[nt][ks].h[7] = (__bf16)u1.w;
      } else {
        #pragma unroll
        for (int j = 0; j < 8; ++j) {
          const int f = f0 + j;
          wfrag[nt][ks].h[j] = (gg < FC_DIM && f < FC_DIM)
                                   ? (__bf16)Wf2[gg * FC_DIM + f] : (__bf16)0.0f;
        }
      }
    }
  }
  float bf2r[7];
  #pragma unroll
  for (int nt = 0; nt < 7; ++nt) {
    const int gg = nt * 16 + l15;
    bf2r[nt] = (gg < FC_DIM) ? bf2[gg] : 0.0f;
  }

  // ---- Phase A: gather embedding rows, fp32 -> bf16 -> LDS ----
  {
    const int r = t >> 3;                 // 0..31
    const int c0 = (t & 7) * 8;           // 8 cols per thread
    const int item = seq_var[b * SEQ_LEN + r];
    const float4 v0 = *(const float4*)(item_emb + item * EMBED_DIM + c0);
    const float4 v1 = *(const float4*)(item_emb + item * EMBED_DIM + c0 + 4);
    FragAB e;
    e.h[0] = (__bf16)v0.x; e.h[1] = (__bf16)v0.y;
    e.h[2] = (__bf16)v0.z; e.h[3] = (__bf16)v0.w;
    e.h[4] = (__bf16)v1.x; e.h[5] = (__bf16)v1.y;
    e.h[6] = (__bf16)v1.z; e.h[7] = (__bf16)v1.w;
    *(short8*)(emb_s + r * ES + c0) = e.s;   // byte off = r*160 + c0*2, 16B-aligned
  }
  for (int i = t; i < SEQ_LEN * 32; i += 256) {   // zero f-pad cols 100..131
    const int r = i >> 5, c = FC_DIM + (i & 31);
    A_s[r * AS + c] = 0.f;
    B_s[r * AS + c] = 0.f;
  }
  __syncthreads();

  // ---- Phase B: first FC via MFMA. o<100 -> A_s col o; 100<=o<200 -> B_s col o-100
  for (int nt = w; nt < 13; nt += 4) {
    const int o = nt * 16 + l15;
    int wr = 0, wc = 0;
    bool valid = true;
    if (o < FC_DIM)            { wr = o;          wc = 0;  }   // Wa = W1[:, :64]
    else if (o < 2 * FC_DIM)   { wr = o - FC_DIM; wc = 64; }   // Wb = W1[:, 64:]
    else valid = false;
    FragAB bfr[2];
    #pragma unroll
    for (int ks = 0; ks < 2; ++ks) {
      if (valid) {
        const float* p = W1 + wr * 128 + wc + ks * 32 + q * 8;  // 32B-aligned
        const float4 u0 = *(const float4*)p;
        const float4 u1 = *(const float4*)(p + 4);
        bfr[ks].h[0] = (__bf16)u0.x; bfr[ks].h[1] = (__bf16)u0.y;
        bfr[ks].h[2] = (__bf16)u0.z; bfr[ks].h[3] = (__bf16)u0.w;
        bfr[ks].h[4] = (__bf16)u1.x; bfr[ks].h[5] = (__bf16)u1.y;
        bfr[ks].h[6] = (__bf16)u1.z; bfr[ks].h[7] = (__bf16)u1.w;
      } else {
        #pragma unroll
        for (int j = 0; j < 8; ++j) bfr[ks].h[j] = (__bf16)0.0f;
      }
    }
    const float b1v = (o >= FC_DIM && o < 2 * FC_DIM) ? b1[o - FC_DIM] : 0.f;
    #pragma unroll
    for (int mt = 0; mt < 2; ++mt) {
      FragAB afr[2];
      #pragma unroll
      for (int ks = 0; ks < 2; ++ks)
        afr[ks].s = *(const short8*)(emb_s + (mt * 16 + l15) * ES + ks * 32 + q * 8);
      f32x4 acc = {0.f, 0.f, 0.f, 0.f};
      #pragma unroll
      for (int ks = 0; ks < 2; ++ks)
        acc = __builtin_amdgcn_mfma_f32_16x16x32_bf16(afr[ks].s, bfr[ks].s, acc, 0, 0, 0);
      const int row = mt * 16 + q * 4;   // D: col = lane&15, row = quad*4 + reg
      if (o < FC_DIM) {
        #pragma unroll
        for (int r = 0; r < 4; ++r) A_s[(row + r) * AS + o] = acc[r];
      } else if (o < 2 * FC_DIM) {
        #pragma unroll
        for (int r = 0; r < 4; ++r) B_s[(row + r) * AS + (o - FC_DIM)] = acc[r] + b1v;
      }
    }
  }
  __syncthreads();

  // ---- Phase D: pair loop. Group = (c-half: 16 rows, 8 consecutive a's) ----
  float colsum[7];
  #pragma unroll
  for (int nt = 0; nt < 7; ++nt) colsum[nt] = 0.f;

  for (int g = w; g < 8; g += 4) {       // 2 groups per wave
    const int c = (g & 1) * 16 + l15;    // this lane's c-row (MFMA m-index)
    const int a0 = (g >> 1) * 8;
    const float4* ap = (const float4*)(A_s + c * AS);
    float areg[32];                      // f = ks*8.. in A-fragment order
    #pragma unroll
    for (int ks = 0; ks < 4; ++ks) {
      const float4 v0 = ap[ks * 8 + q * 2];
      const float4 v1 = ap[ks * 8 + q * 2 + 1];
      areg[ks*8+0] = v0.x; areg[ks*8+1] = v0.y; areg[ks*8+2] = v0.z; areg[ks*8+3] = v0.w;
      areg[ks*8+4] = v1.x; areg[ks*8+5] = v1.y; areg[ks*8+6] = v1.z; areg[ks*8+7] = v1.w;
    }
    for (int ai = 0; ai < 8; ++ai) {
      const float4* bp = (const float4*)(B_s + (a0 + ai) * AS);  // broadcast reads
      FragAB hf[4];
      #pragma unroll
      for (int ks = 0; ks < 4; ++ks) {
        const float4 b0 = bp[ks * 8 + q * 2];
        const float4 b1f = bp[ks * 8 + q * 2 + 1];
        hf[ks].h[0] = (__bf16)fmaxf(areg[ks*8+0] + b0.x, 0.f);
        hf[ks].h[1] = (__bf16)fmaxf(areg[ks*8+1] + b0.y, 0.f);
        hf[ks].h[2] = (__bf16)fmaxf(areg[ks*8+2] + b0.z, 0.f);
        hf[ks].h[3] = (__bf16)fmaxf(areg[ks*8+3] + b0.w, 0.f);
        hf[ks].h[4] = (__bf16)fmaxf(areg[ks*8+4] + b1f.x, 0.f);
        hf[ks].h[5] = (__bf16)fmaxf(areg[ks*8+5] + b1f.y, 0.f);
        hf[ks].h[6] = (__bf16)fmaxf(areg[ks*8+6] + b1f.z, 0.f);
        hf[ks].h[7] = (__bf16)fmaxf(areg[ks*8+7] + b1f.w, 0.f);
      }
      #pragma unroll
      for (int nt = 0; nt < 7; ++nt) {
        f32x4 acc = {0.f, 0.f, 0.f, 0.f};
        #pragma unroll
        for (int ks = 0; ks < 4; ++ks)
          acc = __builtin_amdgcn_mfma_f32_16x16x32_bf16(hf[ks].s, wfrag[nt][ks].s, acc, 0, 0, 0);
        #pragma unroll
        for (int r = 0; r < 4; ++r)
          colsum[nt] += fmaxf(acc[r] + bf2r[nt], 0.f);   // second relu + M-reduce
      }
    }
  }

  // ---- Phase E: reduce colsum across (wave, quad) via LDS ----
  #pragma unroll
  for (int nt = 0; nt < 7; ++nt)
    red_s[(w * 4 + q) * 112 + nt * 16 + l15] = colsum[nt];
  __syncthreads();
  if (t < 112) {
    float s = 0.f;
    #pragma unroll
    for (int r = 0; r < 16; ++r) s += red_s[r * 112 + t];
    x_s[t] = s;
  }
  __syncthreads();

  // ---- Phase F: out[b,w] = b2[iv] + W2[iv,:]·concat(x_s, uemb), pure fp32 ----
  float partial = 0.f;
  if (w < 3) {
    const int iv = item_var[b * 3 + w];
    const int uu = user_var[b];
    for (int idx = l; idx < FC_DIM + EMBED_DIM; idx += 64) {
      const float xv = (idx < FC_DIM)
                           ? x_s[idx]
                           : user_emb[uu * EMBED_DIM + (idx - FC_DIM)];
      partial += W2[iv * (FC_DIM + EMBED_DIM) + idx] * xv;
    }
  }
  red_s[w * 64 + l] = partial;
  __syncthreads();
  if (t < 3) {
    float s = 0.f;
    for (int i = 0; i < 64; ++i) s += red_s[t * 64 + i];
    const int iv = item_var[b * 3 + t];
    out[b * 3 + t] = s + b2[iv];
  }
}

extern "C" void kernel_launch(void* const* d_in, const int* in_sizes, int n_in,
                              void* d_out, int out_size, void* d_ws, size_t ws_size,
                              hipStream_t stream) {
  const int* seq = (const int*)d_in[0];
  const int* usr = (const int*)d_in[1];
  const int* itm = (const int*)d_in[2];
  const float* item_emb = (const float*)d_in[3];
  const float* user_emb = (const float*)d_in[4];
  const float* W2  = (const float*)d_in[5];
  const float* b2  = (const float*)d_in[6];
  const float* W1  = (const float*)d_in[7];
  const float* b1  = (const float*)d_in[8];
  const float* Wf2 = (const float*)d_in[9];
  const float* bf2 = (const float*)d_in[10];
  cosrec_fused<<<BATCH, 256, 0, stream>>>(seq, usr, itm, item_emb, user_emb,
                                          W2, b2, W1, b1, Wf2, bf2,
                                          (float*)d_out);
}